// Round 6
// baseline (495.017 us; speedup 1.0000x reference)
//
#include <hip/hip_runtime.h>
#include <hip/hip_bf16.h>
#include <stdint.h>
#include <stddef.h>

// Problem: B=2, L=2048, D=1024, H=16, HD=64.
// Inputs FP32, output FP32.  Internal pipeline bf16 MFMA.
// R6: transposed attention.  S^T = K*Q^T; its C-layout (P[qrow=l15][key=quad*4+r])
// IS the B-operand layout of mfma_16x16x16 -> pack exp() results in-lane and feed
// PV directly.  No LDS / no volatile asm / no shuffles inside the K-loop =>
// compiler can software-pipeline across steps (R3/R5 were serialized by the
// lgkmcnt(0) memory clobber every iteration; MfmaUtil was stuck at 5.4%).

#define NB     2
#define NH     16
#define SL     2048
#define DH     64
#define DMODEL 1024
#define NSC    4095   // 2L-1

typedef __attribute__((ext_vector_type(8))) short bf16x8;   // 8 bf16 in 4 VGPRs
typedef __attribute__((ext_vector_type(4))) short bf16x4;
typedef __attribute__((ext_vector_type(4))) float f32x4;

static __device__ __forceinline__ short f2bf(float x) {
  __hip_bfloat16 h = __float2bfloat16(x);
  return *reinterpret_cast<short*>(&h);
}

// ------------------------------------------------------------ fp32 -> bf16
__global__ __launch_bounds__(256) void cvt_bf16_k(const float* __restrict__ src,
                                                  short* __restrict__ dst, int n4) {
  int i = blockIdx.x * 256 + threadIdx.x;
  if (i >= n4) return;
  float4 a = *(const float4*)(src + (size_t)i * 4);
  bf16x4 o;
  o.x = f2bf(a.x); o.y = f2bf(a.y); o.z = f2bf(a.z); o.w = f2bf(a.w);
  *(bf16x4*)(dst + (size_t)i * 4) = o;
}

// ---------------------------------------------------------------- TISA bias
__global__ void tisa_bias_k(const float* __restrict__ koff,
                            const float* __restrict__ kamp,
                            const float* __restrict__ kshp,
                            float* __restrict__ scores) {
  int h = blockIdx.y;
  int r = blockIdx.x * 256 + threadIdx.x;
  if (r >= NSC) return;
  float rel = (float)(r - (SL - 1));
  float acc = 0.f;
#pragma unroll
  for (int k = 0; k < 16; ++k) {
    float o = koff[h * 16 + k];
    float a = kamp[h * 16 + k];
    float s = fabsf(kshp[h * 16 + k]);
    float d = o - rel;
    acc += a * __expf(-s * d * d);
  }
  scores[h * NSC + r] = acc;
}

// ---------------------------------------------------------------- QKV GEMM
// C[m,n] = sum_k x[m,k] * w_in[n,k].  n>>10: 0=k, 1=v, 2=q (reference split order).
// k,q stored [bh][l][hd] bf16 (q pre-scaled by 1/8); v transposed [bh][hd][l] bf16.
__global__ __launch_bounds__(256) void qkv_gemm_k(
    const short* __restrict__ A, const short* __restrict__ Bw,
    __hip_bfloat16* __restrict__ kbuf, __hip_bfloat16* __restrict__ vbufT,
    __hip_bfloat16* __restrict__ qbuf) {
  __shared__ __align__(16) short As[128 * 64];
  __shared__ __align__(16) short Bs[128 * 64];
  const int tid  = threadIdx.x;
  const int lane = tid & 63;
  const int wv   = tid >> 6;
  const int l15  = lane & 15, quad = lane >> 4;
  const int wm = (wv & 1) * 64, wn = (wv >> 1) * 64;
  const int m0 = blockIdx.y * 128, n0 = blockIdx.x * 128;

  f32x4 acc[4][4];
#pragma unroll
  for (int r = 0; r < 4; ++r)
#pragma unroll
    for (int c = 0; c < 4; ++c) acc[r][c] = (f32x4){0.f, 0.f, 0.f, 0.f};

  for (int kt = 0; kt < 16; ++kt) {
    const int k0 = kt * 64;
#pragma unroll
    for (int it = 0; it < 4; ++it) {
      const int e8  = it * 256 + tid;
      const int row = e8 >> 3;
      const int col = (e8 & 7) * 8;
      __builtin_amdgcn_global_load_lds(
          (const __attribute__((address_space(1))) void*)(A + (size_t)(m0 + row) * DMODEL + k0 + col),
          (__attribute__((address_space(3))) void*)(&As[e8 * 8]), 16, 0, 0);
      __builtin_amdgcn_global_load_lds(
          (const __attribute__((address_space(1))) void*)(Bw + (size_t)(n0 + row) * DMODEL + k0 + col),
          (__attribute__((address_space(3))) void*)(&Bs[e8 * 8]), 16, 0, 0);
    }
    __syncthreads();
#pragma unroll
    for (int ki = 0; ki < 64; ki += 32) {
      bf16x8 af[4], bfv[4];
#pragma unroll
      for (int r = 0; r < 4; ++r)
        af[r] = *(const bf16x8*)&As[(wm + r * 16 + l15) * 64 + ki + quad * 8];
#pragma unroll
      for (int c = 0; c < 4; ++c)
        bfv[c] = *(const bf16x8*)&Bs[(wn + c * 16 + l15) * 64 + ki + quad * 8];
#pragma unroll
      for (int r = 0; r < 4; ++r)
#pragma unroll
        for (int c = 0; c < 4; ++c)
          acc[r][c] = __builtin_amdgcn_mfma_f32_16x16x32_bf16(af[r], bfv[c], acc[r][c], 0, 0, 0);
    }
    __syncthreads();
  }
#pragma unroll
  for (int c = 0; c < 4; ++c) {
    const int n     = n0 + wn + c * 16 + l15;
    const int which = n >> 10;          // 0=k, 1=v, 2=q
    const int hh    = (n >> 6) & 15;
    const int hd    = n & 63;
#pragma unroll
    for (int r = 0; r < 4; ++r) {
      const int m0r = m0 + wm + r * 16 + quad * 4;   // 4 consecutive m (g=0..3)
      const int bb  = m0r >> 11;
      const int ll  = m0r & 2047;
      if (which == 1) {
        bf16x4 pk;
#pragma unroll
        for (int g = 0; g < 4; ++g) pk[g] = f2bf(acc[r][c][g]);
        *(bf16x4*)&vbufT[(((size_t)bb * NH + hh) * DH + hd) * SL + ll] = pk;   // 8B store
      } else if (which == 0) {
#pragma unroll
        for (int g = 0; g < 4; ++g)
          kbuf[(((size_t)bb * NH + hh) * SL + ll + g) * DH + hd] = __float2bfloat16(acc[r][c][g]);
      } else {
#pragma unroll
        for (int g = 0; g < 4; ++g)
          qbuf[(((size_t)bb * NH + hh) * SL + ll + g) * DH + hd] = __float2bfloat16(acc[r][c][g] * 0.125f);
      }
    }
  }
}

// ---------------------------------------------------------------- attention
// Transposed split-K flash.  Wave = 16 q-rows x 1024 keys.
// S^T via mfma32(kf, qf); PV^T via mfma16(vf, pf) with pf packed in-lane.
// No LDS / barriers in the K-loop.  Halves combined via LDS once at end.
__global__ __launch_bounds__(256, 4) void attn_k(
    const __hip_bfloat16* __restrict__ qbuf, const __hip_bfloat16* __restrict__ kbuf,
    const __hip_bfloat16* __restrict__ vbufT, const float* __restrict__ scores,
    float* __restrict__ out) {
  __shared__ __align__(16) float Comb[2][16][64];         // 8192 B
  __shared__ float CombL[2][16];                          // 128 B
  const int bh   = blockIdx.x;
  const int b    = bh >> 4, h = bh & 15;
  const int tid  = threadIdx.x;
  const int lane = tid & 63;
  const int wv   = tid >> 6;
  const int l15  = lane & 15, quad = lane >> 4;
  const int half = wv & 1, rp = wv >> 1;
  const int i0   = blockIdx.y * 32 + rp * 16;    // wave's first query row
  const int jb   = half * (SL / 2);
  const __hip_bfloat16* qb = qbuf + (size_t)bh * SL * DH;
  const __hip_bfloat16* kb = kbuf + (size_t)bh * SL * DH;
  const __hip_bfloat16* vb = vbufT + (size_t)bh * DH * SL;
  const float* sc = scores + h * NSC;

  // Q frags (rows of Q, pre-scaled by 1/8); used as the B operand of S^T = K*Q^T
  bf16x8 qf0 = *(const bf16x8*)&qb[(size_t)(i0 + l15) * DH + quad * 8];
  bf16x8 qf1 = *(const bf16x8*)&qb[(size_t)(i0 + l15) * DH + 32 + quad * 8];

  f32x4 o[4];      // O^T accumulators: O[qrow=i0+l15][hd = d*16 + quad*4 + g]
#pragma unroll
  for (int d = 0; d < 4; ++d) o[d] = (f32x4){0.f, 0.f, 0.f, 0.f};
  float lsum = 0.f;   // per-lane; qrow = l15, summed over this lane's keys

  for (int j0 = jb; j0 < jb + SL / 2; j0 += 64) {
    // ---- loads (no consumer until MFMA; compiler pipelines across steps) ----
    bf16x8 kf0[4], kf1[4];
#pragma unroll
    for (int sub = 0; sub < 4; ++sub) {
      const __hip_bfloat16* krow = &kb[(size_t)(j0 + sub * 16 + l15) * DH];
      kf0[sub] = *(const bf16x8*)&krow[quad * 8];
      kf1[sub] = *(const bf16x8*)&krow[32 + quad * 8];
    }
    bf16x4 vf[4][4];   // V^T A-frags for mfma16: V^T[d*16+l15][j0+sub*16+quad*4 ..+3]
#pragma unroll
    for (int d = 0; d < 4; ++d) {
      const __hip_bfloat16* vrow = &vb[(size_t)(d * 16 + l15) * SL + j0];
#pragma unroll
      for (int sub = 0; sub < 4; ++sub)
        vf[d][sub] = *(const bf16x4*)&vrow[sub * 16 + quad * 4];
    }
    float4 bv[4];      // bias, reversed: bv[3-r] is the value for reg r
#pragma unroll
    for (int sub = 0; sub < 4; ++sub)
      bv[sub] = *(const float4*)(sc + (i0 + l15) - (j0 + sub * 16 + quad * 4) - 3 + 2047);

    // ---- S^T = K * Q^T (C-layout: key=quad*4+r, qrow=l15) ----
    f32x4 s[4];
#pragma unroll
    for (int sub = 0; sub < 4; ++sub) {
      f32x4 z = (f32x4){0.f, 0.f, 0.f, 0.f};
      z      = __builtin_amdgcn_mfma_f32_16x16x32_bf16(kf0[sub], qf0, z, 0, 0, 0);
      s[sub] = __builtin_amdgcn_mfma_f32_16x16x32_bf16(kf1[sub], qf1, z, 0, 0, 0);
    }
    // ---- p = exp(s + bias); pack in-lane into PV B-frags (max-free softmax) ----
    bf16x4 pf[4];
#pragma unroll
    for (int sub = 0; sub < 4; ++sub) {
      const float* bp = (const float*)&bv[sub];
#pragma unroll
      for (int r = 0; r < 4; ++r) {
        const float p = __expf(s[sub][r] + bp[3 - r]);
        lsum += p;
        pf[sub][r] = f2bf(p);
      }
    }
    // ---- O^T += V^T * P^T  (B-frag = pf directly; no transform) ----
#pragma unroll
    for (int d = 0; d < 4; ++d)
#pragma unroll
      for (int sub = 0; sub < 4; ++sub)
        o[d] = __builtin_amdgcn_mfma_f32_16x16x16bf16_1k(vf[d][sub], pf[sub], o[d], 0, 0, 0);
  }

  // ---- reduce lsum across the 4 quads (qrow = l15 in all of them) ----
  lsum += __shfl_xor(lsum, 16);
  lsum += __shfl_xor(lsum, 32);

  // ---- combine halves: odd wave publishes, even wave adds + stores ----
  if (half) {
#pragma unroll
    for (int d = 0; d < 4; ++d)
      *(f32x4*)&Comb[rp][l15][d * 16 + quad * 4] = o[d];
    if (quad == 0) CombL[rp][l15] = lsum;
  }
  __syncthreads();
  if (!half) {
    const float inv = 1.f / (lsum + CombL[rp][l15]);
    float* orow = out + (((size_t)b * SL + i0 + l15) * NH + h) * DH;
#pragma unroll
    for (int d = 0; d < 4; ++d) {
      const f32x4 cmb = *(const f32x4*)&Comb[rp][l15][d * 16 + quad * 4];
      f32x4 v;
#pragma unroll
      for (int g = 0; g < 4; ++g) v[g] = (o[d][g] + cmb[g]) * inv;
      *(f32x4*)&orow[d * 16 + quad * 4] = v;
    }
  }
}

// ---------------------------------------------------------------- launch
extern "C" void kernel_launch(void* const* d_in, const int* in_sizes, int n_in,
                              void* d_out, int out_size, void* d_ws, size_t ws_size,
                              hipStream_t stream) {
  const float* x    = (const float*)d_in[0];   // (B,L,D) fp32
  const float* w    = (const float*)d_in[1];   // (3D,D) fp32
  const float* koff = (const float*)d_in[2];   // (H,K) fp32
  const float* kamp = (const float*)d_in[3];
  const float* kshp = (const float*)d_in[4];
  float* out = (float*)d_out;                  // (B,L,D) fp32

  const size_t per = (size_t)NB * NH * SL * DH;               // 4,194,304 elems
  const size_t nx  = (size_t)NB * SL * DMODEL;                // 4,194,304
  const size_t nw  = (size_t)3 * DMODEL * DMODEL;             // 3,145,728

  __hip_bfloat16* kbuf  = (__hip_bfloat16*)d_ws;              // 8 MB
  __hip_bfloat16* vbufT = kbuf + per;                         // 8 MB
  __hip_bfloat16* qbuf  = vbufT + per;                        // 8 MB
  float* scores = (float*)(qbuf + per);                       // 262,080 B
  short* xbf    = (short*)(scores + (size_t)NH * NSC + 4);    // 8 MB
  short* wbf    = xbf + nx;                                   // 6 MB   => ~38.3 MB total

  cvt_bf16_k<<<(int)(nx / 4 + 255) / 256, 256, 0, stream>>>(x, xbf, (int)(nx / 4));
  cvt_bf16_k<<<(int)(nw / 4 + 255) / 256, 256, 0, stream>>>(w, wbf, (int)(nw / 4));
  tisa_bias_k<<<dim3(16, NH), 256, 0, stream>>>(koff, kamp, kshp, scores);
  qkv_gemm_k<<<dim3(24, 32), 256, 0, stream>>>(xbf, wbf, kbuf, vbufT, qbuf);
  attn_k<<<dim3(NB * NH, SL / 32), 256, 0, stream>>>(qbuf, kbuf, vbufT, scores, out);
}

// Round 8
// 202.723 us; speedup vs baseline: 2.4418x; 2.4418x over previous
//
#include <hip/hip_runtime.h>
#include <hip/hip_bf16.h>
#include <stdint.h>
#include <stddef.h>

// Problem: B=2, L=2048, D=1024, H=16, HD=64.
// Inputs FP32, output FP32.  Internal pipeline bf16 MFMA.
// R8: fixes R7's K-staging bug (contiguous copy vs stride-72 frag reads).
// Both K and V^T now staged with the 9-chunks-per-row mapping: chunk c ->
// row r=c/9, subchunk s=c%9; LDS dest is forced-contiguous (c*16B) which
// lands at stride-72 rows; s=8 chunk overlap-reads next row start (pad,
// never consumed).  72 shorts = 36 dwords = 4 mod 32 -> 2-way LDS conflicts
// (free) for both b128 K reads and b64 V reads.

#define NB     2
#define NH     16
#define SL     2048
#define DH     64
#define DMODEL 1024
#define SCP    4096   // padded scores row stride (floats); 4095 real

typedef __attribute__((ext_vector_type(8))) short bf16x8;   // 8 bf16 in 4 VGPRs
typedef __attribute__((ext_vector_type(4))) short bf16x4;
typedef __attribute__((ext_vector_type(4))) float f32x4;

static __device__ __forceinline__ short f2bf(float x) {
  __hip_bfloat16 h = __float2bfloat16(x);
  return *reinterpret_cast<short*>(&h);
}
#define GLD(g, l) __builtin_amdgcn_global_load_lds( \
    (const __attribute__((address_space(1))) void*)(g), \
    (__attribute__((address_space(3))) void*)(l), 16, 0, 0)

// ------------------------------------------------------------ fp32 -> bf16
__global__ __launch_bounds__(256) void cvt_bf16_k(const float* __restrict__ src,
                                                  short* __restrict__ dst, int n4) {
  int i = blockIdx.x * 256 + threadIdx.x;
  if (i >= n4) return;
  float4 a = *(const float4*)(src + (size_t)i * 4);
  bf16x4 o;
  o.x = f2bf(a.x); o.y = f2bf(a.y); o.z = f2bf(a.z); o.w = f2bf(a.w);
  *(bf16x4*)(dst + (size_t)i * 4) = o;
}

// ---------------------------------------------------------------- TISA bias
__global__ void tisa_bias_k(const float* __restrict__ koff,
                            const float* __restrict__ kamp,
                            const float* __restrict__ kshp,
                            float* __restrict__ scores) {
  int h = blockIdx.y;
  int r = blockIdx.x * 256 + threadIdx.x;
  if (r >= 4095) return;
  float rel = (float)(r - (SL - 1));
  float acc = 0.f;
#pragma unroll
  for (int k = 0; k < 16; ++k) {
    float o = koff[h * 16 + k];
    float a = kamp[h * 16 + k];
    float s = fabsf(kshp[h * 16 + k]);
    float d = o - rel;
    acc += a * __expf(-s * d * d);
  }
  scores[h * SCP + r] = acc;
}

// ---------------------------------------------------------------- QKV GEMM
// C[m,n] = sum_k x[m,k] * w_in[n,k].  n>>10: 0=k, 1=v, 2=q (reference split order).
// k,q stored [bh][l][hd] bf16 (q pre-scaled by 1/8); v transposed [bh][hd][l] bf16.
__global__ __launch_bounds__(256) void qkv_gemm_k(
    const short* __restrict__ A, const short* __restrict__ Bw,
    __hip_bfloat16* __restrict__ kbuf, __hip_bfloat16* __restrict__ vbufT,
    __hip_bfloat16* __restrict__ qbuf) {
  __shared__ __align__(16) short As[128 * 64];
  __shared__ __align__(16) short Bs[128 * 64];
  const int tid  = threadIdx.x;
  const int lane = tid & 63;
  const int wv   = tid >> 6;
  const int l15  = lane & 15, quad = lane >> 4;
  const int wm = (wv & 1) * 64, wn = (wv >> 1) * 64;
  const int m0 = blockIdx.y * 128, n0 = blockIdx.x * 128;

  f32x4 acc[4][4];
#pragma unroll
  for (int r = 0; r < 4; ++r)
#pragma unroll
    for (int c = 0; c < 4; ++c) acc[r][c] = (f32x4){0.f, 0.f, 0.f, 0.f};

  for (int kt = 0; kt < 16; ++kt) {
    const int k0 = kt * 64;
#pragma unroll
    for (int it = 0; it < 4; ++it) {
      const int e8  = it * 256 + tid;
      const int row = e8 >> 3;
      const int col = (e8 & 7) * 8;
      GLD(A + (size_t)(m0 + row) * DMODEL + k0 + col, &As[e8 * 8]);
      GLD(Bw + (size_t)(n0 + row) * DMODEL + k0 + col, &Bs[e8 * 8]);
    }
    __syncthreads();
#pragma unroll
    for (int ki = 0; ki < 64; ki += 32) {
      bf16x8 af[4], bfv[4];
#pragma unroll
      for (int r = 0; r < 4; ++r)
        af[r] = *(const bf16x8*)&As[(wm + r * 16 + l15) * 64 + ki + quad * 8];
#pragma unroll
      for (int c = 0; c < 4; ++c)
        bfv[c] = *(const bf16x8*)&Bs[(wn + c * 16 + l15) * 64 + ki + quad * 8];
#pragma unroll
      for (int r = 0; r < 4; ++r)
#pragma unroll
        for (int c = 0; c < 4; ++c)
          acc[r][c] = __builtin_amdgcn_mfma_f32_16x16x32_bf16(af[r], bfv[c], acc[r][c], 0, 0, 0);
    }
    __syncthreads();
  }
#pragma unroll
  for (int c = 0; c < 4; ++c) {
    const int n     = n0 + wn + c * 16 + l15;
    const int which = n >> 10;          // 0=k, 1=v, 2=q
    const int hh    = (n >> 6) & 15;
    const int hd    = n & 63;
#pragma unroll
    for (int r = 0; r < 4; ++r) {
      const int m0r = m0 + wm + r * 16 + quad * 4;   // 4 consecutive m (g=0..3)
      const int bb  = m0r >> 11;
      const int ll  = m0r & 2047;
      if (which == 1) {
        bf16x4 pk;
#pragma unroll
        for (int g = 0; g < 4; ++g) pk[g] = f2bf(acc[r][c][g]);
        *(bf16x4*)&vbufT[(((size_t)bb * NH + hh) * DH + hd) * SL + ll] = pk;   // 8B store
      } else if (which == 0) {
#pragma unroll
        for (int g = 0; g < 4; ++g)
          kbuf[(((size_t)bb * NH + hh) * SL + ll + g) * DH + hd] = __float2bfloat16(acc[r][c][g]);
      } else {
#pragma unroll
        for (int g = 0; g < 4; ++g)
          qbuf[(((size_t)bb * NH + hh) * SL + ll + g) * DH + hd] = __float2bfloat16(acc[r][c][g] * 0.125f);
      }
    }
  }
}

// ---------------------------------------------------------------- attention
// Block = 4 waves = 64 q-rows of one (b,h); all 2048 keys in 32 steps of 64.
// Per step: stage K (64 rows x 64, LDS stride 72) + V^T (64 rows x 64, stride
// 72) via global_load_lds 9-chunk mapping; bias diag staged once per block.
// S^T = K*Q^T (mfma32); P packed in-lane -> PV B-frag (mfma16).  Max-free
// softmax; lsum reduced once at end.
__global__ __launch_bounds__(256, 4) void attn_k(
    const __hip_bfloat16* __restrict__ qbuf, const __hip_bfloat16* __restrict__ kbuf,
    const __hip_bfloat16* __restrict__ vbufT, const float* __restrict__ scores,
    float* __restrict__ out) {
  __shared__ __align__(16) short Ks[64 * 72];    // 9216 B
  __shared__ __align__(16) short Vs[64 * 72];    // 9216 B
  __shared__ __align__(16) float Bss[2112];      // 8448 B   => 26.9 KB total
  const int bh   = blockIdx.x;
  const int b    = bh >> 4, h = bh & 15;
  const int tid  = threadIdx.x;
  const int lane = tid & 63;
  const int wv   = tid >> 6;
  const int l15  = lane & 15, quad = lane >> 4;
  const int i0b  = blockIdx.y * 64;          // block's first q row
  const int i0   = i0b + wv * 16;            // wave's first q row
  const __hip_bfloat16* qb = qbuf + (size_t)bh * SL * DH;
  const short* kb = (const short*)(kbuf + (size_t)bh * SL * DH);
  const short* vb = (const short*)(vbufT + (size_t)bh * DH * SL);
  const float* sc = scores + h * SCP;

  // ---- stage bias diagonal once: Bss[t] = sc[i0b + t], t in [0,2112) ----
  {
    const float* bsrc = sc + i0b;                 // 16B aligned (i0b mult of 64)
    GLD(bsrc + (size_t)tid * 4, &Bss[tid * 4]);
    GLD(bsrc + (size_t)(256 + tid) * 4, &Bss[(256 + tid) * 4]);
    if (tid < 16) GLD(bsrc + (size_t)(512 + tid) * 4, &Bss[(512 + tid) * 4]);
  }

  // Q frags (rows of Q, pre-scaled); B operand of S^T = K*Q^T
  bf16x8 qf0 = *(const bf16x8*)&qb[(size_t)(i0 + l15) * DH + quad * 8];
  bf16x8 qf1 = *(const bf16x8*)&qb[(size_t)(i0 + l15) * DH + 32 + quad * 8];

  f32x4 o[4];      // O^T: O[qrow=i0+l15][hd = d*16 + quad*4 + g]
#pragma unroll
  for (int d = 0; d < 4; ++d) o[d] = (f32x4){0.f, 0.f, 0.f, 0.f};
  float lsum = 0.f;

  for (int j0 = 0; j0 < SL; j0 += 64) {
    // ---- stage K tile: chunk c -> row r=c/9, sub s=c%9; LDS stride 72 ----
    // LDS[72r + t] = kb[(j0+r)*64 + t]  (t in [0,64); s=8 chunk = pad)
    {
      const short* ksrc = kb + (size_t)j0 * DH;
      int c0 = tid;          int r0 = c0 / 9, s0 = c0 - r0 * 9;
      GLD(ksrc + (size_t)r0 * DH + s0 * 8, &Ks[c0 * 8]);
      int c1 = 256 + tid;    int r1 = c1 / 9, s1 = c1 - r1 * 9;
      GLD(ksrc + (size_t)r1 * DH + s1 * 8, &Ks[c1 * 8]);
      if (tid < 64) {
        int c2 = 512 + tid;  int r2 = c2 / 9, s2 = c2 - r2 * 9;
        GLD(ksrc + (size_t)r2 * DH + s2 * 8, &Ks[c2 * 8]);
      }
    }
    // ---- stage V^T tile: same mapping; LDS[72r + t] = vb[r*SL + j0 + t] ----
    {
      int c0 = tid;          int r0 = c0 / 9, s0 = c0 - r0 * 9;
      GLD(vb + (size_t)r0 * SL + j0 + s0 * 8, &Vs[c0 * 8]);
      int c1 = 256 + tid;    int r1 = c1 / 9, s1 = c1 - r1 * 9;
      GLD(vb + (size_t)r1 * SL + j0 + s1 * 8, &Vs[c1 * 8]);
      if (tid < 64) {
        int c2 = 512 + tid;  int r2 = c2 / 9, s2 = c2 - r2 * 9;
        GLD(vb + (size_t)r2 * SL + j0 + s2 * 8, &Vs[c2 * 8]);
      }
    }
    __syncthreads();

    // ---- S^T = K * Q^T (C-layout: key=quad*4+r, qrow=l15) ----
    f32x4 s[4];
#pragma unroll
    for (int sub = 0; sub < 4; ++sub) {
      const short* kr = &Ks[(sub * 16 + l15) * 72];
      bf16x8 a0 = *(const bf16x8*)&kr[quad * 8];
      bf16x8 a1 = *(const bf16x8*)&kr[32 + quad * 8];
      f32x4 z = (f32x4){0.f, 0.f, 0.f, 0.f};
      z      = __builtin_amdgcn_mfma_f32_16x16x32_bf16(a0, qf0, z, 0, 0, 0);
      s[sub] = __builtin_amdgcn_mfma_f32_16x16x32_bf16(a1, qf1, z, 0, 0, 0);
    }
    // ---- p = exp(s + bias); pack in-lane into PV B-frags ----
    bf16x4 pf[4];
    const int bb0 = wv * 16 + l15 - j0 + 2047 - quad * 4;
#pragma unroll
    for (int sub = 0; sub < 4; ++sub) {
      const int ib = bb0 - sub * 16;
#pragma unroll
      for (int r = 0; r < 4; ++r) {
        const float p = __expf(s[sub][r] + Bss[ib - r]);
        lsum += p;
        pf[sub][r] = f2bf(p);
      }
    }
    // ---- O^T += V^T * P^T ----
#pragma unroll
    for (int d = 0; d < 4; ++d) {
      const short* vr = &Vs[(d * 16 + l15) * 72];
#pragma unroll
      for (int sub = 0; sub < 4; ++sub) {
        bf16x4 vfrag = *(const bf16x4*)&vr[sub * 16 + quad * 4];
        o[d] = __builtin_amdgcn_mfma_f32_16x16x16bf16_1k(vfrag, pf[sub], o[d], 0, 0, 0);
      }
    }
    __syncthreads();
  }

  // ---- reduce lsum across quads (qrow = l15 in all) ----
  lsum += __shfl_xor(lsum, 16);
  lsum += __shfl_xor(lsum, 32);
  const float inv = 1.f / lsum;
  float* orow = out + (((size_t)b * SL + i0 + l15) * NH + h) * DH;
#pragma unroll
  for (int d = 0; d < 4; ++d) {
    f32x4 v;
#pragma unroll
    for (int g = 0; g < 4; ++g) v[g] = o[d][g] * inv;
    *(f32x4*)&orow[d * 16 + quad * 4] = v;
  }
}

// ---------------------------------------------------------------- launch
extern "C" void kernel_launch(void* const* d_in, const int* in_sizes, int n_in,
                              void* d_out, int out_size, void* d_ws, size_t ws_size,
                              hipStream_t stream) {
  const float* x    = (const float*)d_in[0];   // (B,L,D) fp32
  const float* w    = (const float*)d_in[1];   // (3D,D) fp32
  const float* koff = (const float*)d_in[2];   // (H,K) fp32
  const float* kamp = (const float*)d_in[3];
  const float* kshp = (const float*)d_in[4];
  float* out = (float*)d_out;                  // (B,L,D) fp32

  const size_t per = (size_t)NB * NH * SL * DH;               // 4,194,304 elems
  const size_t nx  = (size_t)NB * SL * DMODEL;                // 4,194,304
  const size_t nw  = (size_t)3 * DMODEL * DMODEL;             // 3,145,728

  __hip_bfloat16* kbuf  = (__hip_bfloat16*)d_ws;              // 8 MB
  __hip_bfloat16* vbufT = kbuf + per;                         // 8 MB
  __hip_bfloat16* qbuf  = vbufT + per;                        // 8 MB
  float* scores = (float*)(qbuf + per);                       // 16*4096*4 = 256 KB
  short* xbf    = (short*)(scores + (size_t)NH * SCP);        // 8 MB
  short* wbf    = xbf + nx;                                   // 6 MB   => ~38.3 MB total

  cvt_bf16_k<<<(int)(nx / 4 + 255) / 256, 256, 0, stream>>>(x, xbf, (int)(nx / 4));
  cvt_bf16_k<<<(int)(nw / 4 + 255) / 256, 256, 0, stream>>>(w, wbf, (int)(nw / 4));
  tisa_bias_k<<<dim3(16, NH), 256, 0, stream>>>(koff, kamp, kshp, scores);
  qkv_gemm_k<<<dim3(24, 32), 256, 0, stream>>>(xbf, wbf, kbuf, vbufT, qbuf);
  attn_k<<<dim3(NB * NH, SL / 64), 256, 0, stream>>>(qbuf, kbuf, vbufT, scores, out);
}

// Round 9
// 202.640 us; speedup vs baseline: 2.4428x; 1.0004x over previous
//
#include <hip/hip_runtime.h>
#include <hip/hip_bf16.h>
#include <stdint.h>
#include <stddef.h>

// Problem: B=2, L=2048, D=1024, H=16, HD=64.
// Inputs FP32, output FP32.  Internal pipeline bf16 MFMA.
// R9: attn was LDS-read-BW bound (frag reads scale as 1/W, W = qrows/wave).
// W: 16 -> 32 via mfma_f32_32x32x16_bf16 for both QK^T and PV.  Block = 2
// waves x 32 qrows = 64 qrows; V frag reads become b128; MFMA inst count
// halves.  P^T B-frag assembled with one shfl_xor(32) + select per 16-key
// chunk (C-layout quads are split across half-waves).

#define NB     2
#define NH     16
#define SL     2048
#define DH     64
#define DMODEL 1024
#define SCP    4096   // padded scores row stride (floats); 4095 real

typedef __attribute__((ext_vector_type(8)))  short bf16x8;
typedef __attribute__((ext_vector_type(4)))  short bf16x4;
typedef __attribute__((ext_vector_type(4)))  float f32x4;
typedef __attribute__((ext_vector_type(16))) float f32x16;

static __device__ __forceinline__ short f2bf(float x) {
  __hip_bfloat16 h = __float2bfloat16(x);
  return *reinterpret_cast<short*>(&h);
}
static __device__ __forceinline__ long long bf4_to_ll(bf16x4 v) {
  long long r; __builtin_memcpy(&r, &v, 8); return r;
}
static __device__ __forceinline__ bf16x4 ll_to_bf4(long long v) {
  bf16x4 r; __builtin_memcpy(&r, &v, 8); return r;
}
#define GLD(g, l) __builtin_amdgcn_global_load_lds( \
    (const __attribute__((address_space(1))) void*)(g), \
    (__attribute__((address_space(3))) void*)(l), 16, 0, 0)

// ------------------------------------------------------------ fp32 -> bf16
__global__ __launch_bounds__(256) void cvt_bf16_k(const float* __restrict__ src,
                                                  short* __restrict__ dst, int n4) {
  int i = blockIdx.x * 256 + threadIdx.x;
  if (i >= n4) return;
  float4 a = *(const float4*)(src + (size_t)i * 4);
  bf16x4 o;
  o.x = f2bf(a.x); o.y = f2bf(a.y); o.z = f2bf(a.z); o.w = f2bf(a.w);
  *(bf16x4*)(dst + (size_t)i * 4) = o;
}

// ---------------------------------------------------------------- TISA bias
__global__ void tisa_bias_k(const float* __restrict__ koff,
                            const float* __restrict__ kamp,
                            const float* __restrict__ kshp,
                            float* __restrict__ scores) {
  int h = blockIdx.y;
  int r = blockIdx.x * 256 + threadIdx.x;
  if (r >= 4095) return;
  float rel = (float)(r - (SL - 1));
  float acc = 0.f;
#pragma unroll
  for (int k = 0; k < 16; ++k) {
    float o = koff[h * 16 + k];
    float a = kamp[h * 16 + k];
    float s = fabsf(kshp[h * 16 + k]);
    float d = o - rel;
    acc += a * __expf(-s * d * d);
  }
  scores[h * SCP + r] = acc;
}

// ---------------------------------------------------------------- QKV GEMM
// C[m,n] = sum_k x[m,k] * w_in[n,k].  n>>10: 0=k, 1=v, 2=q (reference split order).
// k,q stored [bh][l][hd] bf16 (q pre-scaled by 1/8); v transposed [bh][hd][l] bf16.
__global__ __launch_bounds__(256) void qkv_gemm_k(
    const short* __restrict__ A, const short* __restrict__ Bw,
    __hip_bfloat16* __restrict__ kbuf, __hip_bfloat16* __restrict__ vbufT,
    __hip_bfloat16* __restrict__ qbuf) {
  __shared__ __align__(16) short As[128 * 64];
  __shared__ __align__(16) short Bs[128 * 64];
  const int tid  = threadIdx.x;
  const int lane = tid & 63;
  const int wv   = tid >> 6;
  const int l15  = lane & 15, quad = lane >> 4;
  const int wm = (wv & 1) * 64, wn = (wv >> 1) * 64;
  const int m0 = blockIdx.y * 128, n0 = blockIdx.x * 128;

  f32x4 acc[4][4];
#pragma unroll
  for (int r = 0; r < 4; ++r)
#pragma unroll
    for (int c = 0; c < 4; ++c) acc[r][c] = (f32x4){0.f, 0.f, 0.f, 0.f};

  for (int kt = 0; kt < 16; ++kt) {
    const int k0 = kt * 64;
#pragma unroll
    for (int it = 0; it < 4; ++it) {
      const int e8  = it * 256 + tid;
      const int row = e8 >> 3;
      const int col = (e8 & 7) * 8;
      GLD(A + (size_t)(m0 + row) * DMODEL + k0 + col, &As[e8 * 8]);
      GLD(Bw + (size_t)(n0 + row) * DMODEL + k0 + col, &Bs[e8 * 8]);
    }
    __syncthreads();
#pragma unroll
    for (int ki = 0; ki < 64; ki += 32) {
      bf16x8 af[4], bfv[4];
#pragma unroll
      for (int r = 0; r < 4; ++r)
        af[r] = *(const bf16x8*)&As[(wm + r * 16 + l15) * 64 + ki + quad * 8];
#pragma unroll
      for (int c = 0; c < 4; ++c)
        bfv[c] = *(const bf16x8*)&Bs[(wn + c * 16 + l15) * 64 + ki + quad * 8];
#pragma unroll
      for (int r = 0; r < 4; ++r)
#pragma unroll
        for (int c = 0; c < 4; ++c)
          acc[r][c] = __builtin_amdgcn_mfma_f32_16x16x32_bf16(af[r], bfv[c], acc[r][c], 0, 0, 0);
    }
    __syncthreads();
  }
#pragma unroll
  for (int c = 0; c < 4; ++c) {
    const int n     = n0 + wn + c * 16 + l15;
    const int which = n >> 10;          // 0=k, 1=v, 2=q
    const int hh    = (n >> 6) & 15;
    const int hd    = n & 63;
#pragma unroll
    for (int r = 0; r < 4; ++r) {
      const int m0r = m0 + wm + r * 16 + quad * 4;   // 4 consecutive m (g=0..3)
      const int bb  = m0r >> 11;
      const int ll  = m0r & 2047;
      if (which == 1) {
        bf16x4 pk;
#pragma unroll
        for (int g = 0; g < 4; ++g) pk[g] = f2bf(acc[r][c][g]);
        *(bf16x4*)&vbufT[(((size_t)bb * NH + hh) * DH + hd) * SL + ll] = pk;   // 8B store
      } else if (which == 0) {
#pragma unroll
        for (int g = 0; g < 4; ++g)
          kbuf[(((size_t)bb * NH + hh) * SL + ll + g) * DH + hd] = __float2bfloat16(acc[r][c][g]);
      } else {
#pragma unroll
        for (int g = 0; g < 4; ++g)
          qbuf[(((size_t)bb * NH + hh) * SL + ll + g) * DH + hd] = __float2bfloat16(acc[r][c][g] * 0.125f);
      }
    }
  }
}

// ---------------------------------------------------------------- attention
// Block = 2 waves x 32 qrows = 64 qrows of one (b,h); 32 key-steps of 64.
// Per step: stage K + V^T (stride-72, 9-chunk GLD mapping, R8-verified) and
// bias diag once per block.  Per key-halftile kt (32 keys):
//   S^T = K * Q^T       : 4x mfma_f32_32x32x16_bf16 (A=K frag, B=Q frag)
//   p = exp(s+bias)     : 16 exps; packed bf16x4 per reg-quad
//   P^T B-frags         : shfl_xor(32) quad swap + select (C quads straddle
//                         half-waves; qrow=lane&31 matches B-frag n)
//   O^T += V^T * P^T    : 4x mfma_f32_32x32x16_bf16 (A=V^T b128 frags)
__global__ __launch_bounds__(128, 2) void attn_k(
    const __hip_bfloat16* __restrict__ qbuf, const __hip_bfloat16* __restrict__ kbuf,
    const __hip_bfloat16* __restrict__ vbufT, const float* __restrict__ scores,
    float* __restrict__ out) {
  __shared__ __align__(16) short Ks[64 * 72];    // 9216 B
  __shared__ __align__(16) short Vs[64 * 72];    // 9216 B
  __shared__ __align__(16) float Bss[2112];      // 8448 B   => 26.9 KB total
  const int bh   = blockIdx.x;
  const int b    = bh >> 4, h = bh & 15;
  const int tid  = threadIdx.x;                  // 0..127
  const int lane = tid & 63;
  const int wv   = tid >> 6;                     // 0..1
  const int n32  = lane & 31, hf = lane >> 5;
  const int i0b  = blockIdx.y * 64;              // block's first q row
  const int i0   = i0b + wv * 32;                // wave's first q row
  const __hip_bfloat16* qb = qbuf + (size_t)bh * SL * DH;
  const short* kb = (const short*)(kbuf + (size_t)bh * SL * DH);
  const short* vb = (const short*)(vbufT + (size_t)bh * DH * SL);
  const float* sc = scores + h * SCP;

  // ---- stage bias diagonal once: Bss[t] = sc[i0b + t], t in [0,2112) ----
  {
    const float* bsrc = sc + i0b;
#pragma unroll
    for (int i = 0; i < 4; ++i)
      GLD(bsrc + (size_t)(i * 128 + tid) * 4, &Bss[(i * 128 + tid) * 4]);
    if (tid < 16) GLD(bsrc + (size_t)(512 + tid) * 4, &Bss[(512 + tid) * 4]);
  }

  // Q frags: B[k = hf*8+j][n = qrow = n32] per 16-k chunk kc (HD = 4 chunks)
  bf16x8 qf[4];
#pragma unroll
  for (int kc = 0; kc < 4; ++kc)
    qf[kc] = *(const bf16x8*)&qb[(size_t)(i0 + n32) * DH + kc * 16 + hf * 8];

  f32x16 ot[2];    // O^T: hd = dt*32 + (r&3)+8*(r>>2)+4*hf, qrow = n32
#pragma unroll
  for (int dt = 0; dt < 2; ++dt)
#pragma unroll
    for (int r = 0; r < 16; ++r) ot[dt][r] = 0.f;
  float lsum = 0.f;

  for (int j0 = 0; j0 < SL; j0 += 64) {
    // ---- stage K tile: chunk c -> row r=c/9, sub s=c%9; LDS stride 72 ----
    {
      const short* ksrc = kb + (size_t)j0 * DH;
#pragma unroll
      for (int i = 0; i < 4; ++i) {
        int c = i * 128 + tid; int r = c / 9, s = c - r * 9;
        GLD(ksrc + (size_t)r * DH + s * 8, &Ks[c * 8]);
      }
      if (tid < 64) {
        int c = 512 + tid; int r = c / 9, s = c - r * 9;
        GLD(ksrc + (size_t)r * DH + s * 8, &Ks[c * 8]);
      }
    }
    // ---- stage V^T tile: same mapping; LDS[72r + t] = vb[r*SL + j0 + t] ----
    {
#pragma unroll
      for (int i = 0; i < 4; ++i) {
        int c = i * 128 + tid; int r = c / 9, s = c - r * 9;
        GLD(vb + (size_t)r * SL + j0 + s * 8, &Vs[c * 8]);
      }
      if (tid < 64) {
        int c = 512 + tid; int r = c / 9, s = c - r * 9;
        GLD(vb + (size_t)r * SL + j0 + s * 8, &Vs[c * 8]);
      }
    }
    __syncthreads();

#pragma unroll
    for (int kt = 0; kt < 2; ++kt) {
      // ---- S^T = K * Q^T: C[key-in-tile][qrow], key = (r&3)+8*(r>>2)+4hf ----
      f32x16 st;
#pragma unroll
      for (int r = 0; r < 16; ++r) st[r] = 0.f;
#pragma unroll
      for (int kc = 0; kc < 4; ++kc) {
        bf16x8 kf = *(const bf16x8*)&Ks[(kt * 32 + n32) * 72 + kc * 16 + hf * 8];
        st = __builtin_amdgcn_mfma_f32_32x32x16_bf16(kf, qf[kc], st, 0, 0, 0);
      }
      // ---- p = exp(s + bias); pack per reg-quad ----
      bf16x4 pk[4];
      const int tb0 = wv * 32 + n32 - j0 - kt * 32 - 4 * hf + 2047;
#pragma unroll
      for (int g = 0; g < 4; ++g) {
        const int tb = tb0 - 8 * g;
#pragma unroll
        for (int i = 0; i < 4; ++i) {
          const float p = __expf(st[g * 4 + i] + Bss[tb - i]);
          lsum += p;
          pk[g][i] = f2bf(p);
        }
      }
      // ---- assemble P^T B-frags: swap quads across half-waves ----
      // kc16=0 (keys 0-15 of tile): h=0 needs own g0 + partner g0; h=1: partner g1 + own g1
      long long s0 = hf ? bf4_to_ll(pk[0]) : bf4_to_ll(pk[1]);
      bf16x4 r0 = ll_to_bf4(__shfl_xor(s0, 32));
      bf16x8 pf0 = hf == 0 ? __builtin_shufflevector(pk[0], r0, 0, 1, 2, 3, 4, 5, 6, 7)
                           : __builtin_shufflevector(r0, pk[1], 0, 1, 2, 3, 4, 5, 6, 7);
      // kc16=1 (keys 16-31): same with g2/g3
      long long s1 = hf ? bf4_to_ll(pk[2]) : bf4_to_ll(pk[3]);
      bf16x4 r1 = ll_to_bf4(__shfl_xor(s1, 32));
      bf16x8 pf1 = hf == 0 ? __builtin_shufflevector(pk[2], r1, 0, 1, 2, 3, 4, 5, 6, 7)
                           : __builtin_shufflevector(r1, pk[3], 0, 1, 2, 3, 4, 5, 6, 7);
      // ---- O^T += V^T * P^T ----
#pragma unroll
      for (int dt = 0; dt < 2; ++dt) {
        const short* vr = &Vs[(dt * 32 + n32) * 72 + kt * 32];
        bf16x8 vf0 = *(const bf16x8*)&vr[hf * 8];
        bf16x8 vf1 = *(const bf16x8*)&vr[16 + hf * 8];
        ot[dt] = __builtin_amdgcn_mfma_f32_32x32x16_bf16(vf0, pf0, ot[dt], 0, 0, 0);
        ot[dt] = __builtin_amdgcn_mfma_f32_32x32x16_bf16(vf1, pf1, ot[dt], 0, 0, 0);
      }
    }
    __syncthreads();
  }

  // ---- lsum: per qrow, keys split across half-waves only ----
  lsum += __shfl_xor(lsum, 32);
  const float inv = 1.f / lsum;
  float* orow = out + (((size_t)b * SL + i0 + n32) * NH + h) * DH;
#pragma unroll
  for (int dt = 0; dt < 2; ++dt)
#pragma unroll
    for (int g = 0; g < 4; ++g) {
      f32x4 v;
#pragma unroll
      for (int i = 0; i < 4; ++i) v[i] = ot[dt][g * 4 + i] * inv;
      *(f32x4*)&orow[dt * 32 + 8 * g + 4 * hf] = v;
    }
}

// ---------------------------------------------------------------- launch
extern "C" void kernel_launch(void* const* d_in, const int* in_sizes, int n_in,
                              void* d_out, int out_size, void* d_ws, size_t ws_size,
                              hipStream_t stream) {
  const float* x    = (const float*)d_in[0];   // (B,L,D) fp32
  const float* w    = (const float*)d_in[1];   // (3D,D) fp32
  const float* koff = (const float*)d_in[2];   // (H,K) fp32
  const float* kamp = (const float*)d_in[3];
  const float* kshp = (const float*)d_in[4];
  float* out = (float*)d_out;                  // (B,L,D) fp32

  const size_t per = (size_t)NB * NH * SL * DH;               // 4,194,304 elems
  const size_t nx  = (size_t)NB * SL * DMODEL;                // 4,194,304
  const size_t nw  = (size_t)3 * DMODEL * DMODEL;             // 3,145,728

  __hip_bfloat16* kbuf  = (__hip_bfloat16*)d_ws;              // 8 MB
  __hip_bfloat16* vbufT = kbuf + per;                         // 8 MB
  __hip_bfloat16* qbuf  = vbufT + per;                        // 8 MB
  float* scores = (float*)(qbuf + per);                       // 256 KB
  short* xbf    = (short*)(scores + (size_t)NH * SCP);        // 8 MB
  short* wbf    = xbf + nx;                                   // 6 MB   => ~38.3 MB total

  cvt_bf16_k<<<(int)(nx / 4 + 255) / 256, 256, 0, stream>>>(x, xbf, (int)(nx / 4));
  cvt_bf16_k<<<(int)(nw / 4 + 255) / 256, 256, 0, stream>>>(w, wbf, (int)(nw / 4));
  tisa_bias_k<<<dim3(16, NH), 256, 0, stream>>>(koff, kamp, kshp, scores);
  qkv_gemm_k<<<dim3(24, 32), 256, 0, stream>>>(xbf, wbf, kbuf, vbufT, qbuf);
  attn_k<<<dim3(NB * NH, SL / 64), 128, 0, stream>>>(qbuf, kbuf, vbufT, scores, out);
}

// Round 10
// 197.343 us; speedup vs baseline: 2.5084x; 1.0268x over previous
//
#include <hip/hip_runtime.h>
#include <hip/hip_bf16.h>
#include <stdint.h>
#include <stddef.h>

// Problem: B=2, L=2048, D=1024, H=16, HD=64.
// Inputs FP32, output FP32.  Internal pipeline bf16 MFMA.
// R10: attn_k is at its structural plateau (873 TF eff, 37% ceiling; R9's
// LDS-read halving was neutral).  This round attacks the ~124us "rest":
//  - qkv_gemm epilogue via LDS transpose: v stores were 8B at 4KB lane
//    stride (64 lines/inst!); now all three slots store 16B line-optimal.
//    which-slot is block-uniform (slot = 8 blocks of 128 cols).
//  - cvt_x + cvt_w + bias merged into one prep_k: 5 launches -> 3.

#define NB     2
#define NH     16
#define SL     2048
#define DH     64
#define DMODEL 1024
#define SCP    4096   // padded scores row stride (floats); 4095 real
#define CTS    136    // epilogue LDS row stride (shorts): 16B-aligned rows

typedef __attribute__((ext_vector_type(8)))  short bf16x8;
typedef __attribute__((ext_vector_type(4)))  short bf16x4;
typedef __attribute__((ext_vector_type(4)))  float f32x4;
typedef __attribute__((ext_vector_type(16))) float f32x16;

static __device__ __forceinline__ short f2bf(float x) {
  __hip_bfloat16 h = __float2bfloat16(x);
  return *reinterpret_cast<short*>(&h);
}
static __device__ __forceinline__ long long bf4_to_ll(bf16x4 v) {
  long long r; __builtin_memcpy(&r, &v, 8); return r;
}
static __device__ __forceinline__ bf16x4 ll_to_bf4(long long v) {
  bf16x4 r; __builtin_memcpy(&r, &v, 8); return r;
}
#define GLD(g, l) __builtin_amdgcn_global_load_lds( \
    (const __attribute__((address_space(1))) void*)(g), \
    (__attribute__((address_space(3))) void*)(l), 16, 0, 0)

// ---------------------------------------------------- prep: cvt x, cvt w, bias
// grid: [0,4096) cvt x (1,048,576 float4s), [4096,7168) cvt w (786,432),
// [7168,7424) bias (16 heads x 16 row-chunks).  Branches block-uniform.
__global__ __launch_bounds__(256) void prep_k(
    const float* __restrict__ x, const float* __restrict__ w,
    const float* __restrict__ koff, const float* __restrict__ kamp,
    const float* __restrict__ kshp,
    short* __restrict__ xbf, short* __restrict__ wbf,
    float* __restrict__ scores) {
  const int bx = blockIdx.x, tid = threadIdx.x;
  if (bx < 7168) {
    const float* src = (bx < 4096) ? x : w;
    short* dst       = (bx < 4096) ? xbf : wbf;
    const int i      = (bx < 4096 ? bx : bx - 4096) * 256 + tid;
    float4 a = *(const float4*)(src + (size_t)i * 4);
    bf16x4 o;
    o.x = f2bf(a.x); o.y = f2bf(a.y); o.z = f2bf(a.z); o.w = f2bf(a.w);
    *(bf16x4*)(dst + (size_t)i * 4) = o;
  } else {
    const int idx = bx - 7168;
    const int h = idx >> 4;
    const int r = (idx & 15) * 256 + tid;
    if (r >= 4095) return;
    float rel = (float)(r - (SL - 1));
    float acc = 0.f;
#pragma unroll
    for (int k = 0; k < 16; ++k) {
      float o = koff[h * 16 + k];
      float a = kamp[h * 16 + k];
      float s = fabsf(kshp[h * 16 + k]);
      float d = o - rel;
      acc += a * __expf(-s * d * d);
    }
    scores[h * SCP + r] = acc;
  }
}

// ---------------------------------------------------------------- QKV GEMM
// C[m,n] = sum_k x[m,k] * w_in[n,k].  Slot (k/v/q) is block-uniform.
// Epilogue: C tile -> LDS (bf16) -> 16B coalesced stores.
// k,q: [bh][l][hd] (q pre-scaled 1/8); v: [bh][hd][l].
__global__ __launch_bounds__(256) void qkv_gemm_k(
    const short* __restrict__ A, const short* __restrict__ Bw,
    __hip_bfloat16* __restrict__ kbuf, __hip_bfloat16* __restrict__ vbufT,
    __hip_bfloat16* __restrict__ qbuf) {
  __shared__ __align__(16) short SM[128 * CTS];   // 34.8 KB; aliases As/Bs
  short* As = SM;                                  // 128*64 shorts
  short* Bs = SM + 128 * 64;                       // 128*64 shorts
  const int tid  = threadIdx.x;
  const int lane = tid & 63;
  const int wv   = tid >> 6;
  const int l15  = lane & 15, quad = lane >> 4;
  const int wm = (wv & 1) * 64, wn = (wv >> 1) * 64;
  const int m0 = blockIdx.y * 128, n0 = blockIdx.x * 128;
  const int which = n0 >> 10;          // 0=k, 1=v, 2=q (block-uniform)

  f32x4 acc[4][4];
#pragma unroll
  for (int r = 0; r < 4; ++r)
#pragma unroll
    for (int c = 0; c < 4; ++c) acc[r][c] = (f32x4){0.f, 0.f, 0.f, 0.f};

  for (int kt = 0; kt < 16; ++kt) {
    const int k0 = kt * 64;
#pragma unroll
    for (int it = 0; it < 4; ++it) {
      const int e8  = it * 256 + tid;
      const int row = e8 >> 3;
      const int col = (e8 & 7) * 8;
      GLD(A + (size_t)(m0 + row) * DMODEL + k0 + col, &As[e8 * 8]);
      GLD(Bw + (size_t)(n0 + row) * DMODEL + k0 + col, &Bs[e8 * 8]);
    }
    __syncthreads();
#pragma unroll
    for (int ki = 0; ki < 64; ki += 32) {
      bf16x8 af[4], bfv[4];
#pragma unroll
      for (int r = 0; r < 4; ++r)
        af[r] = *(const bf16x8*)&As[(wm + r * 16 + l15) * 64 + ki + quad * 8];
#pragma unroll
      for (int c = 0; c < 4; ++c)
        bfv[c] = *(const bf16x8*)&Bs[(wn + c * 16 + l15) * 64 + ki + quad * 8];
#pragma unroll
      for (int r = 0; r < 4; ++r)
#pragma unroll
        for (int c = 0; c < 4; ++c)
          acc[r][c] = __builtin_amdgcn_mfma_f32_16x16x32_bf16(af[r], bfv[c], acc[r][c], 0, 0, 0);
    }
    __syncthreads();
  }

  // ---- epilogue: C/D layout m = wm+r*16+quad*4+g, n = wn+c*16+l15 ----
  const int bb  = m0 >> 11;          // batch (tile never straddles)
  const int llb = m0 & 2047;
  const int hhb = (n0 >> 6) & 15;    // head of col 0 (tile covers 2 heads)
  if (which != 1) {
    // k/q: LDS [m][n] (u16 scatter, quad-disjoint banks) -> b128 row reads
    const float qs = (which == 2) ? 0.125f : 1.0f;
#pragma unroll
    for (int r = 0; r < 4; ++r)
#pragma unroll
      for (int c = 0; c < 4; ++c)
#pragma unroll
        for (int g = 0; g < 4; ++g)
          SM[(wm + r * 16 + quad * 4 + g) * CTS + wn + c * 16 + l15] =
              f2bf(acc[r][c][g] * qs);
    __syncthreads();
    __hip_bfloat16* dst = (which == 0) ? kbuf : qbuf;
#pragma unroll
    for (int i = 0; i < 8; ++i) {
      const int cidx = i * 256 + tid;            // 2048 16B chunks
      const int m = cidx >> 4, ch = cidx & 15;
      bf16x8 val = *(const bf16x8*)&SM[m * CTS + ch * 8];
      const int hh  = hhb + (ch >> 3);
      const int hd0 = (ch & 7) * 8;
      *(bf16x8*)&dst[(((size_t)bb * NH + hh) * SL + llb + m) * DH + hd0] = val;
    }
  } else {
    // v: LDS [n][m] (bf16x4 packed writes) -> b128 row reads -> [hd][l] out
#pragma unroll
    for (int r = 0; r < 4; ++r)
#pragma unroll
      for (int c = 0; c < 4; ++c) {
        bf16x4 pk;
#pragma unroll
        for (int g = 0; g < 4; ++g) pk[g] = f2bf(acc[r][c][g]);
        *(bf16x4*)&SM[(wn + c * 16 + l15) * CTS + wm + r * 16 + quad * 4] = pk;
      }
    __syncthreads();
#pragma unroll
    for (int i = 0; i < 8; ++i) {
      const int cidx = i * 256 + tid;
      const int n = cidx >> 4, ch = cidx & 15;
      bf16x8 val = *(const bf16x8*)&SM[n * CTS + ch * 8];
      const int hh = hhb + (n >> 6);
      const int hd = n & 63;
      *(bf16x8*)&vbufT[(((size_t)bb * NH + hh) * DH + hd) * SL + llb + ch * 8] = val;
    }
  }
}

// ---------------------------------------------------------------- attention
// (unchanged from R9 — verified; at its structural plateau ~79us)
__global__ __launch_bounds__(128, 2) void attn_k(
    const __hip_bfloat16* __restrict__ qbuf, const __hip_bfloat16* __restrict__ kbuf,
    const __hip_bfloat16* __restrict__ vbufT, const float* __restrict__ scores,
    float* __restrict__ out) {
  __shared__ __align__(16) short Ks[64 * 72];    // 9216 B
  __shared__ __align__(16) short Vs[64 * 72];    // 9216 B
  __shared__ __align__(16) float Bss[2112];      // 8448 B   => 26.9 KB total
  const int bh   = blockIdx.x;
  const int b    = bh >> 4, h = bh & 15;
  const int tid  = threadIdx.x;                  // 0..127
  const int lane = tid & 63;
  const int wv   = tid >> 6;                     // 0..1
  const int n32  = lane & 31, hf = lane >> 5;
  const int i0b  = blockIdx.y * 64;              // block's first q row
  const int i0   = i0b + wv * 32;                // wave's first q row
  const __hip_bfloat16* qb = qbuf + (size_t)bh * SL * DH;
  const short* kb = (const short*)(kbuf + (size_t)bh * SL * DH);
  const short* vb = (const short*)(vbufT + (size_t)bh * DH * SL);
  const float* sc = scores + h * SCP;

  {
    const float* bsrc = sc + i0b;
#pragma unroll
    for (int i = 0; i < 4; ++i)
      GLD(bsrc + (size_t)(i * 128 + tid) * 4, &Bss[(i * 128 + tid) * 4]);
    if (tid < 16) GLD(bsrc + (size_t)(512 + tid) * 4, &Bss[(512 + tid) * 4]);
  }

  bf16x8 qf[4];
#pragma unroll
  for (int kc = 0; kc < 4; ++kc)
    qf[kc] = *(const bf16x8*)&qb[(size_t)(i0 + n32) * DH + kc * 16 + hf * 8];

  f32x16 ot[2];    // O^T: hd = dt*32 + (r&3)+8*(r>>2)+4*hf, qrow = n32
#pragma unroll
  for (int dt = 0; dt < 2; ++dt)
#pragma unroll
    for (int r = 0; r < 16; ++r) ot[dt][r] = 0.f;
  float lsum = 0.f;

  for (int j0 = 0; j0 < SL; j0 += 64) {
    {
      const short* ksrc = kb + (size_t)j0 * DH;
#pragma unroll
      for (int i = 0; i < 4; ++i) {
        int c = i * 128 + tid; int r = c / 9, s = c - r * 9;
        GLD(ksrc + (size_t)r * DH + s * 8, &Ks[c * 8]);
      }
      if (tid < 64) {
        int c = 512 + tid; int r = c / 9, s = c - r * 9;
        GLD(ksrc + (size_t)r * DH + s * 8, &Ks[c * 8]);
      }
    }
    {
#pragma unroll
      for (int i = 0; i < 4; ++i) {
        int c = i * 128 + tid; int r = c / 9, s = c - r * 9;
        GLD(vb + (size_t)r * SL + j0 + s * 8, &Vs[c * 8]);
      }
      if (tid < 64) {
        int c = 512 + tid; int r = c / 9, s = c - r * 9;
        GLD(vb + (size_t)r * SL + j0 + s * 8, &Vs[c * 8]);
      }
    }
    __syncthreads();

#pragma unroll
    for (int kt = 0; kt < 2; ++kt) {
      f32x16 st;
#pragma unroll
      for (int r = 0; r < 16; ++r) st[r] = 0.f;
#pragma unroll
      for (int kc = 0; kc < 4; ++kc) {
        bf16x8 kf = *(const bf16x8*)&Ks[(kt * 32 + n32) * 72 + kc * 16 + hf * 8];
        st = __builtin_amdgcn_mfma_f32_32x32x16_bf16(kf, qf[kc], st, 0, 0, 0);
      }
      bf16x4 pk[4];
      const int tb0 = wv * 32 + n32 - j0 - kt * 32 - 4 * hf + 2047;
#pragma unroll
      for (int g = 0; g < 4; ++g) {
        const int tb = tb0 - 8 * g;
#pragma unroll
        for (int i = 0; i < 4; ++i) {
          const float p = __expf(st[g * 4 + i] + Bss[tb - i]);
          lsum += p;
          pk[g][i] = f2bf(p);
        }
      }
      long long s0 = hf ? bf4_to_ll(pk[0]) : bf4_to_ll(pk[1]);
      bf16x4 r0 = ll_to_bf4(__shfl_xor(s0, 32));
      bf16x8 pf0 = hf == 0 ? __builtin_shufflevector(pk[0], r0, 0, 1, 2, 3, 4, 5, 6, 7)
                           : __builtin_shufflevector(r0, pk[1], 0, 1, 2, 3, 4, 5, 6, 7);
      long long s1 = hf ? bf4_to_ll(pk[2]) : bf4_to_ll(pk[3]);
      bf16x4 r1 = ll_to_bf4(__shfl_xor(s1, 32));
      bf16x8 pf1 = hf == 0 ? __builtin_shufflevector(pk[2], r1, 0, 1, 2, 3, 4, 5, 6, 7)
                           : __builtin_shufflevector(r1, pk[3], 0, 1, 2, 3, 4, 5, 6, 7);
#pragma unroll
      for (int dt = 0; dt < 2; ++dt) {
        const short* vr = &Vs[(dt * 32 + n32) * 72 + kt * 32];
        bf16x8 vf0 = *(const bf16x8*)&vr[hf * 8];
        bf16x8 vf1 = *(const bf16x8*)&vr[16 + hf * 8];
        ot[dt] = __builtin_amdgcn_mfma_f32_32x32x16_bf16(vf0, pf0, ot[dt], 0, 0, 0);
        ot[dt] = __builtin_amdgcn_mfma_f32_32x32x16_bf16(vf1, pf1, ot[dt], 0, 0, 0);
      }
    }
    __syncthreads();
  }

  lsum += __shfl_xor(lsum, 32);
  const float inv = 1.f / lsum;
  float* orow = out + (((size_t)b * SL + i0 + n32) * NH + h) * DH;
#pragma unroll
  for (int dt = 0; dt < 2; ++dt)
#pragma unroll
    for (int g = 0; g < 4; ++g) {
      f32x4 v;
#pragma unroll
      for (int i = 0; i < 4; ++i) v[i] = ot[dt][g * 4 + i] * inv;
      *(f32x4*)&orow[dt * 32 + 8 * g + 4 * hf] = v;
    }
}

// ---------------------------------------------------------------- launch
extern "C" void kernel_launch(void* const* d_in, const int* in_sizes, int n_in,
                              void* d_out, int out_size, void* d_ws, size_t ws_size,
                              hipStream_t stream) {
  const float* x    = (const float*)d_in[0];   // (B,L,D) fp32
  const float* w    = (const float*)d_in[1];   // (3D,D) fp32
  const float* koff = (const float*)d_in[2];   // (H,K) fp32
  const float* kamp = (const float*)d_in[3];
  const float* kshp = (const float*)d_in[4];
  float* out = (float*)d_out;                  // (B,L,D) fp32

  const size_t per = (size_t)NB * NH * SL * DH;               // 4,194,304 elems
  const size_t nx  = (size_t)NB * SL * DMODEL;                // 4,194,304
  const size_t nw  = (size_t)3 * DMODEL * DMODEL;             // 3,145,728

  __hip_bfloat16* kbuf  = (__hip_bfloat16*)d_ws;              // 8 MB
  __hip_bfloat16* vbufT = kbuf + per;                         // 8 MB
  __hip_bfloat16* qbuf  = vbufT + per;                        // 8 MB
  float* scores = (float*)(qbuf + per);                       // 256 KB
  short* xbf    = (short*)(scores + (size_t)NH * SCP);        // 8 MB
  short* wbf    = xbf + nx;                                   // 6 MB   => ~38.3 MB total

  prep_k<<<7424, 256, 0, stream>>>(x, w, koff, kamp, kshp, xbf, wbf, scores);
  qkv_gemm_k<<<dim3(24, 32), 256, 0, stream>>>(xbf, wbf, kbuf, vbufT, qbuf);
  attn_k<<<dim3(NB * NH, SL / 64), 128, 0, stream>>>(qbuf, kbuf, vbufT, scores, out);
}